// Round 4
// baseline (485.530 us; speedup 1.0000x reference)
//
#include <hip/hip_runtime.h>
#include <hip/hip_fp16.h>

#define BB 8
#define NN 1024
#define FF 128
#define HH 8

typedef _Float16 f16;
typedef f16  f16x8 __attribute__((ext_vector_type(8)));
typedef f16  f16x4 __attribute__((ext_vector_type(4)));
typedef float f32x4 __attribute__((ext_vector_type(4)));

#define L2E 1.44269504f

// ---------------- fused preprocessing: conv_x | conv_w | adj bitmask ----------------
// blocks 0..511: x->f16; 512..703: w->wB; 704..2751: adj->bitmask
__global__ void k_pre(const float* __restrict__ x, f16* __restrict__ x16a,
                      const float* __restrict__ w1, const float* __restrict__ w2,
                      const float* __restrict__ w3, f16* __restrict__ wB,
                      const float* __restrict__ adj, unsigned* __restrict__ am){
  int bid = blockIdx.x, t = threadIdx.x;
  if (bid < 512){
    int i = (bid*256 + t)*8;
    float4 a = *(const float4*)(x+i), b = *(const float4*)(x+i+4);
    f16x8 v;
    v[0]=(f16)a.x; v[1]=(f16)a.y; v[2]=(f16)a.z; v[3]=(f16)a.w;
    v[4]=(f16)b.x; v[5]=(f16)b.y; v[6]=(f16)b.z; v[7]=(f16)b.w;
    *(f16x8*)(x16a+i) = v;
  } else if (bid < 704){
    int e = (bid-512)*256 + t;                 // 49152 total
    int fc = e & 15, c = (e>>4)&127, h = (e>>11)&7, l = e>>14;
    const float* w = (l==0) ? w1 : ((l==1) ? w2 : w3);
    f16x8 v;
    #pragma unroll
    for(int j=0;j<8;j++) v[j] = (f16)w[(h*128 + fc*8 + j)*128 + c];
    *(f16x8*)(wB + (((l*8+h)*16 + fc)*128 + c)*8) = v;
  } else {
    int wv = t >> 6, lane = t & 63;
    int r = (bid-704)*4 + wv;                  // 0..8191
    const float* row = adj + (long)r*1024;
    for(int g=0; g<16; g++){
      float v = row[g*64 + lane];
      unsigned long long mb = __ballot(v > 0.0f);
      if (lane == 0){
        am[r*32 + 2*g]   = (unsigned)mb;
        am[r*32 + 2*g+1] = (unsigned)(mb >> 32);
      }
    }
  }
}

// ---------------- hp GEMM: hp = x @ w  (+tanh -> s,d) ----------------
// grid: b*64 + h*8 + it   (512 blocks, 256 threads)
// hpB layout: [b][h][jc=node/8][c][8]
__global__ __launch_bounds__(256,3) void k_hp(
    const f16* __restrict__ xin,      // [B][N][128] f16
    const f16* __restrict__ wBl,      // [H][16][128][8]
    const float* __restrict__ asrc, const float* __restrict__ adst,  // [H][128]
    f16* __restrict__ hpB,            // [B][H][128][128][8]
    float* __restrict__ sarr, float* __restrict__ darr)              // [B][H][1024]
{
  __shared__ f16 xs[128*136];     // x tile, later reused as tanh tile
  __shared__ float asl[128], adl[128];
  int t = threadIdx.x;
  int bid = blockIdx.x;
  int it = bid & 7, h = (bid>>3)&7, b = bid>>6;
  int i0 = it*128;
  {
    const f16* src = xin + (long)(b*1024 + i0)*128;
    int fc = t & 15, r0 = t >> 4;
    #pragma unroll
    for(int p=0;p<8;p++){
      int r = r0 + p*16;
      f16x8 v = *(const f16x8*)(src + r*128 + fc*8);
      *(f16x8*)(xs + r*136 + fc*8) = v;
    }
  }
  if (t < 128){ asl[t] = asrc[h*128+t]; adl[t] = adst[h*128+t]; }
  __syncthreads();

  int lane = t & 63, wv = t>>6, wr = wv>>1, wc = wv&1;
  int mq = lane & 15, quad = lane >> 4;
  f32x4 acc[4][4];
  #pragma unroll
  for(int a=0;a<4;a++)
    #pragma unroll
    for(int c=0;c<4;c++) acc[a][c] = (f32x4){0.f,0.f,0.f,0.f};

  const f16* wh = wBl + h*16*128*8;
  #pragma unroll
  for(int ks=0; ks<4; ks++){
    f16x8 af[4], bf[4];
    #pragma unroll
    for(int mt=0; mt<4; mt++)
      af[mt] = *(const f16x8*)(xs + (wr*64 + mt*16 + mq)*136 + ks*32 + quad*8);
    #pragma unroll
    for(int nt=0; nt<4; nt++){
      int c  = wc*64 + nt*16 + mq;
      int fc = ks*4 + quad;
      bf[nt] = *(const f16x8*)(wh + (fc*128 + c)*8);
    }
    #pragma unroll
    for(int mt=0; mt<4; mt++)
      #pragma unroll
      for(int nt=0; nt<4; nt++)
        acc[mt][nt] = __builtin_amdgcn_mfma_f32_16x16x32_f16(af[mt], bf[nt], acc[mt][nt], 0,0,0);
  }
  __syncthreads();          // xs dead -> reuse as tanh tile
  f16* tt = xs;             // [128][136]
  f16* hpb = hpB + (long)(b*8+h)*128*128*8;
  #pragma unroll
  for(int mt=0; mt<4; mt++){
    #pragma unroll
    for(int nt=0; nt<4; nt++){
      int c = wc*64 + nt*16 + mq;
      f16x4 pk;
      #pragma unroll
      for(int rg=0; rg<4; rg++){
        float v = acc[mt][nt][rg];
        pk[rg] = (f16)v;
        int il = wr*64 + mt*16 + quad*4 + rg;    // 0..127
        float e2 = __expf(2.0f*v);
        float th = 1.0f - 2.0f*__builtin_amdgcn_rcpf(e2 + 1.0f);
        tt[il*136 + c] = (f16)th;
      }
      int il0 = wr*64 + mt*16 + quad*4;
      int inode = i0 + il0;
      *(f16x4*)(hpb + ((long)(inode>>3)*128 + c)*8 + (inode&7)) = pk;  // 8B packed store
    }
  }
  __syncthreads();
  {
    int r = t>>1, hf = t&1;
    float s_p = 0.f, d_p = 0.f;
    #pragma unroll
    for(int q=0;q<8;q++){
      f16x8 tv = *(const f16x8*)(tt + r*136 + hf*64 + q*8);
      #pragma unroll
      for(int j=0;j<8;j++){
        float tvf = (float)tv[j];
        int c = hf*64 + q*8 + j;
        s_p = fmaf(tvf, asl[c], s_p);
        d_p = fmaf(tvf, adl[c], d_p);
      }
    }
    s_p += __shfl_xor(s_p, 1);
    d_p += __shfl_xor(d_p, 1);
    if (hf == 0){
      sarr[(b*8+h)*1024 + i0 + r] = s_p;
      darr[(b*8+h)*1024 + i0 + r] = d_p;
    }
  }
}

// ---------------- attention (j-split, sparse P, double-buffered) ----------------
// grid: 1024 blocks: bid = q*64 + bh, q = it*2 + jh  (same-bh blocks -> same XCD)
__global__ __launch_bounds__(256,6) void k_attn(
    const f16* __restrict__ hpB,      // [B*H][128][128][8]
    const float* __restrict__ sarr, const float* __restrict__ darr,
    const unsigned* __restrict__ am,  // [B*1024][32]
    f16* __restrict__ part,           // [2*64][1024][128] f16, unnormalized
    float* __restrict__ zpart)        // [2*64][1024]
{
  __shared__ float ddl[512];          // log2e-scaled d for this j-half
  __shared__ float wred[4];
  __shared__ f16 Pl[2][128*40];
  int t = threadIdx.x;
  int bid = blockIdx.x;
  int bh = bid & 63, q = bid >> 6;
  int jh = q & 1, it = q >> 1;
  int i0 = it*128, j0 = jh*512;
  int b = bh >> 3;

  // d: global max over ALL 1024 (shared m bound across j-halves), stage scaled half
  {
    float4 v = *(const float4*)(darr + bh*1024 + t*4);
    float mx = fmaxf(fmaxf(v.x,v.y), fmaxf(v.z,v.w));
    #pragma unroll
    for(int o=1;o<64;o<<=1) mx = fmaxf(mx, __shfl_xor(mx, o));
    if ((t&63)==0) wred[t>>6] = mx;
    int base = t*4 - j0;
    if (base >= 0 && base < 512){
      float4 s = make_float4(v.x*L2E, v.y*L2E, v.z*L2E, v.w*L2E);
      *(float4*)(ddl + base) = s;
    }
  }
  __syncthreads();
  float Dml = fmaxf(fmaxf(wred[0],wred[1]), fmaxf(wred[2],wred[3])) * L2E;

  int prow = t>>1, pjg = t&1;
  float srowl = sarr[bh*1024 + i0 + prow] * L2E;
  float ml = srowl + Dml;
  float mrowl = fmaxf(ml, 0.2f*ml);   // log2-domain upper bound of masked scores
  const unsigned* amrow = am + ((long)(b*1024 + i0 + prow))*32 + jh*16;

  int lane = t&63, wv = t>>6, wr = wv>>1, wc = wv&1;
  int mq = lane&15, quad = lane>>4;
  const f16* hpb = hpB + (long)bh*128*128*8;
  f32x4 acc[4][4];
  #pragma unroll
  for(int a=0;a<4;a++)
    #pragma unroll
    for(int c=0;c<4;c++) acc[a][c] = (f32x4){0.f,0.f,0.f,0.f};
  float zacc = 0.f;
  f16x8 zerov = (f16x8){0,0,0,0,0,0,0,0};

  unsigned wcur = amrow[0];
  for(int jt=0; jt<16; jt++){
    // B fragments from global (L2-resident via XCD swizzle)
    f16x8 bf[4];
    #pragma unroll
    for(int nt=0;nt<4;nt++){
      int c  = wc*64 + nt*16 + mq;
      int jc = jh*64 + jt*4 + quad;
      bf[nt] = *(const f16x8*)(hpb + (jc*128 + c)*8);
    }
    unsigned wnx = (jt < 15) ? amrow[jt+1] : 0u;
    // sparse P tile: zero-fill own region, scatter exp at set bits
    f16* Pb = Pl[jt&1];
    f16* myp = Pb + prow*40 + pjg*16;
    *(f16x8*)(myp)     = zerov;
    *(f16x8*)(myp + 8) = zerov;
    unsigned word = (wcur >> (pjg*16)) & 0xffffu;
    const float* dloc = ddl + jt*32 + pjg*16;
    while(word){
      int j = __builtin_ctz(word);
      word &= word - 1u;
      float xl  = srowl + dloc[j];
      float scl = fmaxf(xl, 0.2f*xl);
      float e   = __builtin_amdgcn_exp2f(scl - mrowl);
      zacc += e;
      myp[j] = (f16)e;
    }
    __syncthreads();
    #pragma unroll
    for(int mt=0;mt<4;mt++){
      f16x8 a = *(const f16x8*)(Pb + (wr*64 + mt*16 + mq)*40 + quad*8);
      #pragma unroll
      for(int nt=0;nt<4;nt++)
        acc[mt][nt] = __builtin_amdgcn_mfma_f32_16x16x32_f16(a, bf[nt], acc[mt][nt], 0,0,0);
    }
    wcur = wnx;
  }
  // partial z per row
  zacc += __shfl_xor(zacc, 1);
  if (pjg == 0) zpart[(jh*64 + bh)*1024 + i0 + prow] = zacc;
  // store unnormalized partial sums (f16)
  f16* pout = part + ((long)(jh*64 + bh)*1024 + i0)*128;
  #pragma unroll
  for(int mt=0;mt<4;mt++){
    #pragma unroll
    for(int nt=0;nt<4;nt++){
      int c = wc*64 + nt*16 + mq;
      #pragma unroll
      for(int rg=0;rg<4;rg++){
        int il = wr*64 + mt*16 + quad*4 + rg;
        pout[il*128 + c] = (f16)acc[mt][nt][rg];
      }
    }
  }
}

// ---------------- finalize: combine halves+z, mean heads, bias(+relu), partial node-max ----------------
// 512 blocks x 256: block covers one b, 16 nodes, all 128 channels
__global__ void k_fin(const f16* __restrict__ part, const float* __restrict__ zp,
                      const float* __restrict__ bias,
                      f16* __restrict__ x16, float* __restrict__ pmax, int do_relu){
  __shared__ float pm[16][128];
  int t = threadIdx.x;
  int idx = blockIdx.x*256 + t;   // b(3)|n(10)|c8(4)
  int c8 = idx & 15, n = (idx>>4)&1023, b = idx>>14;
  float s[8];
  #pragma unroll
  for(int j=0;j<8;j++) s[j] = 0.f;
  #pragma unroll
  for(int h=0;h<8;h++){
    int bh = b*8 + h;
    float zi = 0.125f / (zp[bh*1024 + n] + zp[65536 + bh*1024 + n]);
    f16x8 p0 = *(const f16x8*)(part + ((long)bh*1024 + n)*128 + c8*8);
    f16x8 p1 = *(const f16x8*)(part + ((long)(64+bh)*1024 + n)*128 + c8*8);
    #pragma unroll
    for(int j=0;j<8;j++) s[j] = fmaf((float)p0[j] + (float)p1[j], zi, s[j]);
  }
  f16x8 h8;
  float ov[8];
  #pragma unroll
  for(int j=0;j<8;j++){
    float v = s[j] + bias[c8*8 + j];
    if (do_relu) v = fmaxf(v, 0.f);
    ov[j] = v;
    h8[j] = (f16)v;
  }
  if (x16) *(f16x8*)(x16 + ((long)(b*1024+n))*128 + c8*8) = h8;
  #pragma unroll
  for(int j=0;j<8;j++) pm[n&15][c8*8+j] = ov[j];
  __syncthreads();
  if (t < 128){
    float m = pm[0][t];
    #pragma unroll
    for(int r=1;r<16;r++) m = fmaxf(m, pm[r][t]);
    pmax[blockIdx.x*128 + t] = m;   // [b*64+chunk][128]
  }
}

// ---------------- final: max over chunks + predictor ----------------
__global__ void k_pool2(const float* __restrict__ pmax, const float* __restrict__ pw,
                        const float* __restrict__ pb, float* __restrict__ out){
  __shared__ float pl[384];
  int b = blockIdx.x, t = threadIdx.x;
  for(int f = t; f < 384; f += 256){
    int l = f >> 7, c = f & 127;
    const float* p = pmax + l*65536 + b*64*128 + c;
    float mx = -3.4e38f;
    #pragma unroll 8
    for(int k=0;k<64;k++) mx = fmaxf(mx, p[k*128]);
    pl[f] = mx;
  }
  __syncthreads();
  if (t < 64){
    float a0 = 0.f, a1 = 0.f;
    #pragma unroll
    for(int k=0;k<6;k++){
      int f = t + 64*k;
      float v = pl[f];
      a0 = fmaf(v, pw[f*2],   a0);
      a1 = fmaf(v, pw[f*2+1], a1);
    }
    #pragma unroll
    for(int o=1;o<64;o<<=1){ a0 += __shfl_xor(a0,o); a1 += __shfl_xor(a1,o); }
    if (t == 0){ out[b*2] = a0 + pb[0]; out[b*2+1] = a1 + pb[1]; }
  }
}

// ---------------- launcher ----------------
extern "C" void kernel_launch(void* const* d_in, const int* in_sizes, int n_in,
                              void* d_out, int out_size, void* d_ws, size_t ws_size,
                              hipStream_t stream) {
  const float* x   = (const float*)d_in[0];
  const float* adj = (const float*)d_in[1];
  const float* w1  = (const float*)d_in[2];
  const float* as1 = (const float*)d_in[3];
  const float* ad1 = (const float*)d_in[4];
  const float* b1  = (const float*)d_in[5];
  const float* w2  = (const float*)d_in[6];
  const float* as2 = (const float*)d_in[7];
  const float* ad2 = (const float*)d_in[8];
  const float* b2  = (const float*)d_in[9];
  const float* w3  = (const float*)d_in[10];
  const float* as3 = (const float*)d_in[11];
  const float* ad3 = (const float*)d_in[12];
  const float* b3  = (const float*)d_in[13];
  const float* pw  = (const float*)d_in[14];
  const float* pb  = (const float*)d_in[15];

  char* ws = (char*)d_ws;
  f16*      x16a = (f16*)ws;                 ws += (size_t)1048576*2;
  f16*      x16b = (f16*)ws;                 ws += (size_t)1048576*2;
  f16*      wB   = (f16*)ws;                 ws += (size_t)393216*2;
  unsigned* am   = (unsigned*)ws;            ws += (size_t)8*1024*32*4;
  f16*      hpB  = (f16*)ws;                 ws += (size_t)8*8*1024*128*2;
  float*    sarr = (float*)ws;               ws += (size_t)65536*4;
  float*    darr = (float*)ws;               ws += (size_t)65536*4;
  f16*      part = (f16*)ws;                 ws += (size_t)2*64*1024*128*2;
  float*    zp   = (float*)ws;               ws += (size_t)2*65536*4;
  float*    pmax = (float*)ws;               ws += (size_t)3*512*128*4;

  k_pre<<<2752, 256, 0, stream>>>(x, x16a, w1, w2, w3, wB, adj, am);

  // layer 1
  k_hp  <<<512, 256, 0, stream>>>(x16a, wB,            as1, ad1, hpB, sarr, darr);
  k_attn<<<1024,256, 0, stream>>>(hpB, sarr, darr, am, part, zp);
  k_fin <<<512, 256, 0, stream>>>(part, zp, b1, x16b, pmax,           1);
  // layer 2
  k_hp  <<<512, 256, 0, stream>>>(x16b, wB + 131072,   as2, ad2, hpB, sarr, darr);
  k_attn<<<1024,256, 0, stream>>>(hpB, sarr, darr, am, part, zp);
  k_fin <<<512, 256, 0, stream>>>(part, zp, b2, x16a, pmax + 65536,   1);
  // layer 3
  k_hp  <<<512, 256, 0, stream>>>(x16a, wB + 262144,   as3, ad3, hpB, sarr, darr);
  k_attn<<<1024,256, 0, stream>>>(hpB, sarr, darr, am, part, zp);
  k_fin <<<512, 256, 0, stream>>>(part, zp, b3, nullptr, pmax + 131072, 0);

  k_pool2<<<8, 256, 0, stream>>>(pmax, pw, pb, (float*)d_out);
}

// Round 5
// 259.167 us; speedup vs baseline: 1.8734x; 1.8734x over previous
//
#include <hip/hip_runtime.h>
#include <hip/hip_fp16.h>

#define BB 8
#define NN 1024
#define FF 128
#define HH 8

typedef _Float16 f16;
typedef f16  f16x8 __attribute__((ext_vector_type(8)));
typedef f16  f16x4 __attribute__((ext_vector_type(4)));
typedef float f32x4 __attribute__((ext_vector_type(4)));

#define L2E 1.44269504f

// ---------------- fused preprocessing: conv_x | conv_w | adj bitmask ----------------
// blocks 0..511: x->f16; 512..703: w->wB; 704..2751: adj->bitmask
__global__ void k_pre(const float* __restrict__ x, f16* __restrict__ x16a,
                      const float* __restrict__ w1, const float* __restrict__ w2,
                      const float* __restrict__ w3, f16* __restrict__ wB,
                      const float* __restrict__ adj, unsigned* __restrict__ am){
  int bid = blockIdx.x, t = threadIdx.x;
  if (bid < 512){
    int i = (bid*256 + t)*8;
    float4 a = *(const float4*)(x+i), b = *(const float4*)(x+i+4);
    f16x8 v;
    v[0]=(f16)a.x; v[1]=(f16)a.y; v[2]=(f16)a.z; v[3]=(f16)a.w;
    v[4]=(f16)b.x; v[5]=(f16)b.y; v[6]=(f16)b.z; v[7]=(f16)b.w;
    *(f16x8*)(x16a+i) = v;
  } else if (bid < 704){
    int e = (bid-512)*256 + t;                 // 49152 total
    int fc = e & 15, c = (e>>4)&127, h = (e>>11)&7, l = e>>14;
    const float* w = (l==0) ? w1 : ((l==1) ? w2 : w3);
    f16x8 v;
    #pragma unroll
    for(int j=0;j<8;j++) v[j] = (f16)w[(h*128 + fc*8 + j)*128 + c];
    *(f16x8*)(wB + (((l*8+h)*16 + fc)*128 + c)*8) = v;
  } else {
    int wv = t >> 6, lane = t & 63;
    int r = (bid-704)*4 + wv;                  // 0..8191
    const float* row = adj + (long)r*1024;
    for(int g=0; g<16; g++){
      float v = row[g*64 + lane];
      unsigned long long mb = __ballot(v > 0.0f);
      if (lane == 0){
        am[r*32 + 2*g]   = (unsigned)mb;
        am[r*32 + 2*g+1] = (unsigned)(mb >> 32);
      }
    }
  }
}

// ---------------- hp GEMM: hp = x @ w  (+tanh -> s,d) ----------------
// grid: b*64 + h*8 + it   (512 blocks, 256 threads)
// hpB layout: [b][h][jc=node/8][c][8]
// NOTE: acc[4][4] = 64 AGPRs + ~100 VGPRs -> 2 blocks/CU max; (256,3) spills (R4 lesson)
__global__ __launch_bounds__(256,2) void k_hp(
    const f16* __restrict__ xin,      // [B][N][128] f16
    const f16* __restrict__ wBl,      // [H][16][128][8]
    const float* __restrict__ asrc, const float* __restrict__ adst,  // [H][128]
    f16* __restrict__ hpB,            // [B][H][128][128][8]
    float* __restrict__ sarr, float* __restrict__ darr)              // [B][H][1024]
{
  __shared__ f16 xs[128*136];     // x tile, later reused as tanh tile
  __shared__ float asl[128], adl[128];
  int t = threadIdx.x;
  int bid = blockIdx.x;
  int it = bid & 7, h = (bid>>3)&7, b = bid>>6;
  int i0 = it*128;
  {
    const f16* src = xin + (long)(b*1024 + i0)*128;
    int fc = t & 15, r0 = t >> 4;
    #pragma unroll
    for(int p=0;p<8;p++){
      int r = r0 + p*16;
      f16x8 v = *(const f16x8*)(src + r*128 + fc*8);
      *(f16x8*)(xs + r*136 + fc*8) = v;
    }
  }
  if (t < 128){ asl[t] = asrc[h*128+t]; adl[t] = adst[h*128+t]; }
  __syncthreads();

  int lane = t & 63, wv = t>>6, wr = wv>>1, wc = wv&1;
  int mq = lane & 15, quad = lane >> 4;
  f32x4 acc[4][4];
  #pragma unroll
  for(int a=0;a<4;a++)
    #pragma unroll
    for(int c=0;c<4;c++) acc[a][c] = (f32x4){0.f,0.f,0.f,0.f};

  const f16* wh = wBl + h*16*128*8;
  #pragma unroll
  for(int ks=0; ks<4; ks++){
    f16x8 af[4], bf[4];
    #pragma unroll
    for(int mt=0; mt<4; mt++)
      af[mt] = *(const f16x8*)(xs + (wr*64 + mt*16 + mq)*136 + ks*32 + quad*8);
    #pragma unroll
    for(int nt=0; nt<4; nt++){
      int c  = wc*64 + nt*16 + mq;
      int fc = ks*4 + quad;
      bf[nt] = *(const f16x8*)(wh + (fc*128 + c)*8);
    }
    #pragma unroll
    for(int mt=0; mt<4; mt++)
      #pragma unroll
      for(int nt=0; nt<4; nt++)
        acc[mt][nt] = __builtin_amdgcn_mfma_f32_16x16x32_f16(af[mt], bf[nt], acc[mt][nt], 0,0,0);
  }
  __syncthreads();          // xs dead -> reuse as tanh tile
  f16* tt = xs;             // [128][136]
  f16* hpb = hpB + (long)(b*8+h)*128*128*8;
  #pragma unroll
  for(int mt=0; mt<4; mt++){
    #pragma unroll
    for(int nt=0; nt<4; nt++){
      int c = wc*64 + nt*16 + mq;
      f16x4 pk;
      #pragma unroll
      for(int rg=0; rg<4; rg++){
        float v = acc[mt][nt][rg];
        pk[rg] = (f16)v;
        int il = wr*64 + mt*16 + quad*4 + rg;    // 0..127
        float e2 = __expf(2.0f*v);
        float th = 1.0f - 2.0f*__builtin_amdgcn_rcpf(e2 + 1.0f);
        tt[il*136 + c] = (f16)th;
      }
      int il0 = wr*64 + mt*16 + quad*4;
      int inode = i0 + il0;
      *(f16x4*)(hpb + ((long)(inode>>3)*128 + c)*8 + (inode&7)) = pk;  // 8B packed store
    }
  }
  __syncthreads();
  {
    int r = t>>1, hf = t&1;
    float s_p = 0.f, d_p = 0.f;
    #pragma unroll
    for(int q=0;q<8;q++){
      f16x8 tv = *(const f16x8*)(tt + r*136 + hf*64 + q*8);
      #pragma unroll
      for(int j=0;j<8;j++){
        float tvf = (float)tv[j];
        int c = hf*64 + q*8 + j;
        s_p = fmaf(tvf, asl[c], s_p);
        d_p = fmaf(tvf, adl[c], d_p);
      }
    }
    s_p += __shfl_xor(s_p, 1);
    d_p += __shfl_xor(d_p, 1);
    if (hf == 0){
      sarr[(b*8+h)*1024 + i0 + r] = s_p;
      darr[(b*8+h)*1024 + i0 + r] = d_p;
    }
  }
}

// ---------------- attention (j-split, sparse P, double-buffered) ----------------
// grid: 1024 blocks: bid = q*64 + bh, q = it*2 + jh  (same-bh blocks -> same XCD)
// NOTE: acc = 64 AGPRs + 60 VGPRs -> (256,4) is the max; (256,6) spilled 260 MB/launch (R4)
__global__ __launch_bounds__(256,4) void k_attn(
    const f16* __restrict__ hpB,      // [B*H][128][128][8]
    const float* __restrict__ sarr, const float* __restrict__ darr,
    const unsigned* __restrict__ am,  // [B*1024][32]
    f16* __restrict__ part,           // [2*64][1024][128] f16, unnormalized
    float* __restrict__ zpart)        // [2*64][1024]
{
  __shared__ float ddl[512];          // log2e-scaled d for this j-half
  __shared__ float wred[4];
  __shared__ f16 Pl[2][128*40];
  int t = threadIdx.x;
  int bid = blockIdx.x;
  int bh = bid & 63, q = bid >> 6;
  int jh = q & 1, it = q >> 1;
  int i0 = it*128, j0 = jh*512;
  int b = bh >> 3;

  // d: global max over ALL 1024 (shared m bound across j-halves), stage scaled half
  {
    float4 v = *(const float4*)(darr + bh*1024 + t*4);
    float mx = fmaxf(fmaxf(v.x,v.y), fmaxf(v.z,v.w));
    #pragma unroll
    for(int o=1;o<64;o<<=1) mx = fmaxf(mx, __shfl_xor(mx, o));
    if ((t&63)==0) wred[t>>6] = mx;
    int base = t*4 - j0;
    if (base >= 0 && base < 512){
      float4 s = make_float4(v.x*L2E, v.y*L2E, v.z*L2E, v.w*L2E);
      *(float4*)(ddl + base) = s;
    }
  }
  __syncthreads();
  float Dml = fmaxf(fmaxf(wred[0],wred[1]), fmaxf(wred[2],wred[3])) * L2E;

  int prow = t>>1, pjg = t&1;
  float srowl = sarr[bh*1024 + i0 + prow] * L2E;
  float ml = srowl + Dml;
  float mrowl = fmaxf(ml, 0.2f*ml);   // log2-domain upper bound of masked scores
  const unsigned* amrow = am + ((long)(b*1024 + i0 + prow))*32 + jh*16;

  int lane = t&63, wv = t>>6, wr = wv>>1, wc = wv&1;
  int mq = lane&15, quad = lane>>4;
  const f16* hpb = hpB + (long)bh*128*128*8;
  f32x4 acc[4][4];
  #pragma unroll
  for(int a=0;a<4;a++)
    #pragma unroll
    for(int c=0;c<4;c++) acc[a][c] = (f32x4){0.f,0.f,0.f,0.f};
  float zacc = 0.f;
  f16x8 zerov = (f16x8){0,0,0,0,0,0,0,0};

  unsigned wcur = amrow[0];
  for(int jt=0; jt<16; jt++){
    // B fragments from global (L2-resident via XCD swizzle)
    f16x8 bf[4];
    #pragma unroll
    for(int nt=0;nt<4;nt++){
      int c  = wc*64 + nt*16 + mq;
      int jc = jh*64 + jt*4 + quad;
      bf[nt] = *(const f16x8*)(hpb + (jc*128 + c)*8);
    }
    unsigned wnx = (jt < 15) ? amrow[jt+1] : 0u;
    // sparse P tile: zero-fill own region, scatter exp at set bits
    f16* Pb = Pl[jt&1];
    f16* myp = Pb + prow*40 + pjg*16;
    *(f16x8*)(myp)     = zerov;
    *(f16x8*)(myp + 8) = zerov;
    unsigned word = (wcur >> (pjg*16)) & 0xffffu;
    const float* dloc = ddl + jt*32 + pjg*16;
    while(word){
      int j = __builtin_ctz(word);
      word &= word - 1u;
      float xl  = srowl + dloc[j];
      float scl = fmaxf(xl, 0.2f*xl);
      float e   = __builtin_amdgcn_exp2f(scl - mrowl);
      zacc += e;
      myp[j] = (f16)e;
    }
    __syncthreads();
    #pragma unroll
    for(int mt=0;mt<4;mt++){
      f16x8 a = *(const f16x8*)(Pb + (wr*64 + mt*16 + mq)*40 + quad*8);
      #pragma unroll
      for(int nt=0;nt<4;nt++)
        acc[mt][nt] = __builtin_amdgcn_mfma_f32_16x16x32_f16(a, bf[nt], acc[mt][nt], 0,0,0);
    }
    wcur = wnx;
  }
  // partial z per row
  zacc += __shfl_xor(zacc, 1);
  if (pjg == 0) zpart[(jh*64 + bh)*1024 + i0 + prow] = zacc;
  // store unnormalized partial sums (f16)
  f16* pout = part + ((long)(jh*64 + bh)*1024 + i0)*128;
  #pragma unroll
  for(int mt=0;mt<4;mt++){
    #pragma unroll
    for(int nt=0;nt<4;nt++){
      int c = wc*64 + nt*16 + mq;
      #pragma unroll
      for(int rg=0;rg<4;rg++){
        int il = wr*64 + mt*16 + quad*4 + rg;
        pout[il*128 + c] = (f16)acc[mt][nt][rg];
      }
    }
  }
}

// ---------------- finalize: combine halves+z, mean heads, bias(+relu), partial node-max ----------------
// 512 blocks x 256: block covers one b, 16 nodes, all 128 channels
__global__ void k_fin(const f16* __restrict__ part, const float* __restrict__ zp,
                      const float* __restrict__ bias,
                      f16* __restrict__ x16, float* __restrict__ pmax, int do_relu){
  __shared__ float pm[16][128];
  int t = threadIdx.x;
  int idx = blockIdx.x*256 + t;   // b(3)|n(10)|c8(4)
  int c8 = idx & 15, n = (idx>>4)&1023, b = idx>>14;
  float s[8];
  #pragma unroll
  for(int j=0;j<8;j++) s[j] = 0.f;
  #pragma unroll
  for(int h=0;h<8;h++){
    int bh = b*8 + h;
    float zi = 0.125f / (zp[bh*1024 + n] + zp[65536 + bh*1024 + n]);
    f16x8 p0 = *(const f16x8*)(part + ((long)bh*1024 + n)*128 + c8*8);
    f16x8 p1 = *(const f16x8*)(part + ((long)(64+bh)*1024 + n)*128 + c8*8);
    #pragma unroll
    for(int j=0;j<8;j++) s[j] = fmaf((float)p0[j] + (float)p1[j], zi, s[j]);
  }
  f16x8 h8;
  float ov[8];
  #pragma unroll
  for(int j=0;j<8;j++){
    float v = s[j] + bias[c8*8 + j];
    if (do_relu) v = fmaxf(v, 0.f);
    ov[j] = v;
    h8[j] = (f16)v;
  }
  if (x16) *(f16x8*)(x16 + ((long)(b*1024+n))*128 + c8*8) = h8;
  #pragma unroll
  for(int j=0;j<8;j++) pm[n&15][c8*8+j] = ov[j];
  __syncthreads();
  if (t < 128){
    float m = pm[0][t];
    #pragma unroll
    for(int r=1;r<16;r++) m = fmaxf(m, pm[r][t]);
    pmax[blockIdx.x*128 + t] = m;   // [b*64+chunk][128]
  }
}

// ---------------- final: max over chunks + predictor ----------------
__global__ void k_pool2(const float* __restrict__ pmax, const float* __restrict__ pw,
                        const float* __restrict__ pb, float* __restrict__ out){
  __shared__ float pl[384];
  int b = blockIdx.x, t = threadIdx.x;
  for(int f = t; f < 384; f += 256){
    int l = f >> 7, c = f & 127;
    const float* p = pmax + l*65536 + b*64*128 + c;
    float mx = -3.4e38f;
    #pragma unroll 8
    for(int k=0;k<64;k++) mx = fmaxf(mx, p[k*128]);
    pl[f] = mx;
  }
  __syncthreads();
  if (t < 64){
    float a0 = 0.f, a1 = 0.f;
    #pragma unroll
    for(int k=0;k<6;k++){
      int f = t + 64*k;
      float v = pl[f];
      a0 = fmaf(v, pw[f*2],   a0);
      a1 = fmaf(v, pw[f*2+1], a1);
    }
    #pragma unroll
    for(int o=1;o<64;o<<=1){ a0 += __shfl_xor(a0,o); a1 += __shfl_xor(a1,o); }
    if (t == 0){ out[b*2] = a0 + pb[0]; out[b*2+1] = a1 + pb[1]; }
  }
}

// ---------------- launcher ----------------
extern "C" void kernel_launch(void* const* d_in, const int* in_sizes, int n_in,
                              void* d_out, int out_size, void* d_ws, size_t ws_size,
                              hipStream_t stream) {
  const float* x   = (const float*)d_in[0];
  const float* adj = (const float*)d_in[1];
  const float* w1  = (const float*)d_in[2];
  const float* as1 = (const float*)d_in[3];
  const float* ad1 = (const float*)d_in[4];
  const float* b1  = (const float*)d_in[5];
  const float* w2  = (const float*)d_in[6];
  const float* as2 = (const float*)d_in[7];
  const float* ad2 = (const float*)d_in[8];
  const float* b2  = (const float*)d_in[9];
  const float* w3  = (const float*)d_in[10];
  const float* as3 = (const float*)d_in[11];
  const float* ad3 = (const float*)d_in[12];
  const float* b3  = (const float*)d_in[13];
  const float* pw  = (const float*)d_in[14];
  const float* pb  = (const float*)d_in[15];

  char* ws = (char*)d_ws;
  f16*      x16a = (f16*)ws;                 ws += (size_t)1048576*2;
  f16*      x16b = (f16*)ws;                 ws += (size_t)1048576*2;
  f16*      wB   = (f16*)ws;                 ws += (size_t)393216*2;
  unsigned* am   = (unsigned*)ws;            ws += (size_t)8*1024*32*4;
  f16*      hpB  = (f16*)ws;                 ws += (size_t)8*8*1024*128*2;
  float*    sarr = (float*)ws;               ws += (size_t)65536*4;
  float*    darr = (float*)ws;               ws += (size_t)65536*4;
  f16*      part = (f16*)ws;                 ws += (size_t)2*64*1024*128*2;
  float*    zp   = (float*)ws;               ws += (size_t)2*65536*4;
  float*    pmax = (float*)ws;               ws += (size_t)3*512*128*4;

  k_pre<<<2752, 256, 0, stream>>>(x, x16a, w1, w2, w3, wB, adj, am);

  // layer 1
  k_hp  <<<512, 256, 0, stream>>>(x16a, wB,            as1, ad1, hpB, sarr, darr);
  k_attn<<<1024,256, 0, stream>>>(hpB, sarr, darr, am, part, zp);
  k_fin <<<512, 256, 0, stream>>>(part, zp, b1, x16b, pmax,           1);
  // layer 2
  k_hp  <<<512, 256, 0, stream>>>(x16b, wB + 131072,   as2, ad2, hpB, sarr, darr);
  k_attn<<<1024,256, 0, stream>>>(hpB, sarr, darr, am, part, zp);
  k_fin <<<512, 256, 0, stream>>>(part, zp, b2, x16a, pmax + 65536,   1);
  // layer 3
  k_hp  <<<512, 256, 0, stream>>>(x16a, wB + 262144,   as3, ad3, hpB, sarr, darr);
  k_attn<<<1024,256, 0, stream>>>(hpB, sarr, darr, am, part, zp);
  k_fin <<<512, 256, 0, stream>>>(part, zp, b3, nullptr, pmax + 131072, 0);

  k_pool2<<<8, 256, 0, stream>>>(pmax, pw, pb, (float*)d_out);
}